// Round 12
// baseline (362.424 us; speedup 1.0000x reference)
//
#include <hip/hip_runtime.h>
#include <cstdint>
#include <cstddef>

// ---------- types ----------
typedef __attribute__((ext_vector_type(8))) __bf16 bf16x8;
typedef __attribute__((ext_vector_type(8))) unsigned short u16x8;
typedef __attribute__((ext_vector_type(4))) float f32x4;
typedef __attribute__((ext_vector_type(4))) unsigned short u16x4;

__device__ __forceinline__ unsigned short f2bf(float f) {
  unsigned int u = __builtin_bit_cast(unsigned int, f);
  u += 0x7fffu + ((u >> 16) & 1u);           // RNE
  return (unsigned short)(u >> 16);
}
__device__ __forceinline__ float bf2f(unsigned short u) {
  return __builtin_bit_cast(float, ((unsigned int)u) << 16);
}

// counted vmcnt waits (T4): literal immediates via if constexpr
template <int N> __device__ __forceinline__ void wait_vm() {
  if constexpr (N == 0)       asm volatile("s_waitcnt vmcnt(0)" ::: "memory");
  else if constexpr (N == 6)  asm volatile("s_waitcnt vmcnt(6)" ::: "memory");
  else if constexpr (N == 8)  asm volatile("s_waitcnt vmcnt(8)" ::: "memory");
  else if constexpr (N == 12) asm volatile("s_waitcnt vmcnt(12)" ::: "memory");
  else                        asm volatile("s_waitcnt vmcnt(0)" ::: "memory");
}

// ---------- weight cast+transpose, one 64x64 tile (tile id in [0,7168)) ----------
__device__ void wcast_tile(char* smemc, int bid,
    const float* s_img, const float* s_qkv, const float* s_o,
    const float* s_ff1, const float* s_ff2, const float* s_cls,
    unsigned short* d_img, unsigned short* d_qkv, unsigned short* d_o,
    unsigned short* d_ff1, unsigned short* d_ff2, unsigned short* d_cls) {
  float (*tile)[65] = (float (*)[65])smemc;
  const float* src; unsigned short* dst; int K, N, Npad, rel;
  if (bid < 1024)       { src = s_img; dst = d_img; K = 4096; N = 1024; Npad = 1024; rel = bid; }
  else if (bid < 2560)  { rel = bid - 1024; int l = rel / 384; rel -= l * 384;
                          src = s_qkv + (size_t)l * 1024 * 1536; dst = d_qkv + (size_t)l * 1536 * 1024;
                          K = 1024; N = 1536; Npad = 1536; }
  else if (bid < 3072)  { rel = bid - 2560; int l = rel / 128; rel -= l * 128;
                          src = s_o   + (size_t)l * 512 * 1024;  dst = d_o   + (size_t)l * 1024 * 512;
                          K = 512;  N = 1024; Npad = 1024; }
  else if (bid < 4096)  { rel = bid - 3072; int l = rel / 256; rel -= l * 256;
                          src = s_ff1 + (size_t)l * 1024 * 1024; dst = d_ff1 + (size_t)l * 1024 * 1024;
                          K = 1024; N = 1024; Npad = 1024; }
  else if (bid < 5120)  { rel = bid - 4096; int l = rel / 256; rel -= l * 256;
                          src = s_ff2 + (size_t)l * 1024 * 1024; dst = d_ff2 + (size_t)l * 1024 * 1024;
                          K = 1024; N = 1024; Npad = 1024; }
  else                  { rel = bid - 5120; src = s_cls; dst = d_cls; K = 8192; N = 1000; Npad = 1024; }
  int tilesX = Npad >> 6;
  int nx = rel % tilesX, ky = rel / tilesX;
  int n0 = nx << 6, k0 = ky << 6;
  int t = threadIdx.x;
#pragma unroll
  for (int i = 0; i < 4; ++i) {
    int slot = t + i * 256;
    int kk = slot >> 4, cq = slot & 15;
    int n = n0 + cq * 4;
    float4 v;
    if (n + 3 < N) v = *(const float4*)(src + (size_t)(k0 + kk) * N + n);
    else {
      v.x = v.y = v.z = v.w = 0.0f;
      if (n < N)     v.x = src[(size_t)(k0 + kk) * N + n];
      if (n + 1 < N) v.y = src[(size_t)(k0 + kk) * N + n + 1];
      if (n + 2 < N) v.z = src[(size_t)(k0 + kk) * N + n + 2];
      if (n + 3 < N) v.w = src[(size_t)(k0 + kk) * N + n + 3];
    }
    tile[kk][cq * 4 + 0] = v.x;
    tile[kk][cq * 4 + 1] = v.y;
    tile[kk][cq * 4 + 2] = v.z;
    tile[kk][cq * 4 + 3] = v.w;
  }
  __syncthreads();
#pragma unroll
  for (int i = 0; i < 4; ++i) {
    int slot = t + i * 256;
    int n = slot >> 4, kq = slot & 15;
    u16x4 o;
    o.x = f2bf(tile[kq * 4 + 0][n]);
    o.y = f2bf(tile[kq * 4 + 1][n]);
    o.z = f2bf(tile[kq * 4 + 2][n]);
    o.w = f2bf(tile[kq * 4 + 3][n]);
    *(u16x4*)(dst + (size_t)(n0 + n) * K + k0 + kq * 4) = o;
  }
  __syncthreads();
}

// ---------- GEMM pieces (BK=64, NT-threaded staging) ----------
template <int BK, int ITERS, int NT>
__device__ __forceinline__ void stage_tile(const unsigned short* __restrict__ g, int ld,
                                           int k0, char* lbase, int tid) {
  constexpr int CH = BK / 8;           // 16B chunks per row
#pragma unroll
  for (int it = 0; it < ITERS; ++it) {
    int c = tid + it * NT;
    int r = c / CH;
    int slot = c & (CH - 1);
    int gc = slot ^ (r & (CH - 1));    // pre-swizzled global source (m173 pattern)
    const unsigned short* src = g + (size_t)r * ld + (k0 + gc * 8);
    char* dst = lbase + c * 16;        // linear LDS dest
    __builtin_amdgcn_global_load_lds((__attribute__((address_space(1))) void*)src,
                                     (__attribute__((address_space(3))) void*)dst, 16, 0, 0);
  }
}

template <int BK>
__device__ __forceinline__ bf16x8 ld_frag(const char* base, int row, int k8) {
  constexpr int CH = BK / 8;
  int off = row * (BK * 2) + ((k8 ^ (row & (CH - 1))) << 4);   // XOR swizzle (G4)
  return *(const bf16x8*)(base + off);
}

// TM=128, TN=64. NT=256: 4 waves, wave owns 32x64 (MR=2).
//                NT=128: 2 waves, wave owns 64x64 (MR=4) — 2 blocks/CU, better read ratio.
// OMODE: 0=f32 out, 1=bf16 out. 3-buffer pipelined K-loop (counted vmcnt + raw barriers).
template <int TN, int ACT, int OMODE, bool RES, int BK, int NT>
__device__ void gemm_tile(char* smem,
    const unsigned short* __restrict__ A, int lda,
    const unsigned short* __restrict__ BT, int ldb, int Kloop,
    const float* __restrict__ bias, const unsigned short* __restrict__ res,
    float* __restrict__ outF, unsigned short* __restrict__ outB,
    int ldC, int Nstore, int m0, int n0, int koff) {
  constexpr int MR = (NT == 128) ? 4 : 2;
  constexpr int ABYTES = 128 * BK * 2;
  constexpr int BUFS = (128 + TN) * BK * 2;
  constexpr int AITERS = 16 * BK / NT;          // 128*BK*2/16/NT
  constexpr int BITERS = TN * BK / (8 * NT);
  constexpr int VM = AITERS + BITERS;           // VMEM instrs/thread/tile
  const int tid = threadIdx.x;
  const int lane = tid & 63;
  const int wid = tid >> 6;
  const int rowbase = (NT == 128) ? wid * 64 : wid * 32;
  const unsigned short* Ag = A + (size_t)m0 * lda + koff;
  const unsigned short* Bg = BT + (size_t)n0 * ldb + koff;
  f32x4 acc[MR][4];
#pragma unroll
  for (int m = 0; m < MR; m++)
#pragma unroll
    for (int n = 0; n < 4; n++) acc[m][n] = 0.f;
  const int nt = Kloop / BK;
  // prologue: prefetch tiles 0 and 1
  stage_tile<BK, AITERS, NT>(Ag, lda, 0, smem, tid);
  stage_tile<BK, BITERS, NT>(Bg, ldb, 0, smem + ABYTES, tid);
  stage_tile<BK, AITERS, NT>(Ag, lda, BK, smem + BUFS, tid);
  stage_tile<BK, BITERS, NT>(Bg, ldb, BK, smem + BUFS + ABYTES, tid);
  int cur = 0;
  const int rA = lane & 15, kq = lane >> 4;
  for (int t = 0; t < nt; ++t) {
    if (t + 1 < nt) wait_vm<VM>(); else wait_vm<0>();   // tile t landed; t+1 in flight
    __builtin_amdgcn_s_barrier();                       // all waves: t ready, t-1 reads done
    if (t + 2 < nt) {
      int nb = cur + 2; if (nb >= 3) nb -= 3;
      stage_tile<BK, AITERS, NT>(Ag, lda, (t + 2) * BK, smem + nb * BUFS, tid);
      stage_tile<BK, BITERS, NT>(Bg, ldb, (t + 2) * BK, smem + nb * BUFS + ABYTES, tid);
    }
    const char* la = smem + cur * BUFS;
    const char* lb = la + ABYTES;
#pragma unroll
    for (int kk = 0; kk < BK / 32; ++kk) {
      int k8 = kk * 4 + kq;
      bf16x8 af[MR], bfr[4];
#pragma unroll
      for (int m = 0; m < MR; m++) af[m] = ld_frag<BK>(la, rowbase + m * 16 + rA, k8);
#pragma unroll
      for (int n = 0; n < 4; n++) bfr[n] = ld_frag<BK>(lb, n * 16 + rA, k8);
#pragma unroll
      for (int m = 0; m < MR; m++)
#pragma unroll
        for (int n = 0; n < 4; n++)
          acc[m][n] = __builtin_amdgcn_mfma_f32_16x16x32_bf16(af[m], bfr[n], acc[m][n], 0, 0, 0);
    }
    cur = (cur + 1 == 3) ? 0 : cur + 1;
  }
  const int rb = m0 + rowbase + (kq << 2);
  const int cb = n0 + rA;
#pragma unroll
  for (int m = 0; m < MR; m++)
#pragma unroll
    for (int n = 0; n < 4; n++) {
      int cg = cb + n * 16;
      if (cg >= Nstore) continue;
      float bv = bias ? bias[cg] : 0.0f;
#pragma unroll
      for (int j = 0; j < 4; j++) {
        int rg = rb + m * 16 + j;
        float v = acc[m][n][j] + bv;
        if (RES) v += bf2f(res[(size_t)rg * ldC + cg]);
        if (ACT == 1) v = 0.5f * v * (1.0f + erff(v * 0.70710678118654752f));
        if (OMODE == 0) {
          outF[(size_t)rg * ldC + cg] = v;
        } else {
          outB[(size_t)rg * ldC + cg] = f2bf(v);
        }
      }
    }
}

// ---------- fused qkv GEMM + attention, 64-row tiles, XCD-clustered, pipelined ----------
#define SLABW 200   // slab stride in u16: 400B, 16B-aligned, bank-shift 4 per row
__global__ __launch_bounds__(256) void qkvattn(
    const unsigned short* __restrict__ h,      // [2048][1024] bf16
    const unsigned short* __restrict__ BTq,    // [1536][1024] bf16 (layer slice)
    unsigned short* __restrict__ obuf) {       // [2048][512] bf16
  __shared__ __align__(16) char smem[98304];   // 3 x (A 8KB + B 24KB)
  const int tid = threadIdx.x, lane = tid & 63, wid = tid >> 6;
  const int p = blockIdx.x;
  const int xslot = p & 7, rem = p >> 3;
  const int hh = rem & 7;
  const int my = xslot + 8 * (rem >> 3);      // 0..31
  const int m0 = my << 6;
  const int wr = wid >> 1, wc = wid & 1;
  const unsigned short* Ag = h + (size_t)m0 * 1024;
  const unsigned short* Bseg0 = BTq + (size_t)(hh * 64) * 1024;
  const unsigned short* Bseg1 = BTq + (size_t)(512 + hh * 64) * 1024;
  const unsigned short* Bseg2 = BTq + (size_t)(1024 + hh * 64) * 1024;
  constexpr int BUFS = 32768;
  f32x4 acc[2][6];
#pragma unroll
  for (int m = 0; m < 2; m++)
#pragma unroll
    for (int n = 0; n < 6; n++) acc[m][n] = 0.f;
  const int rA = lane & 15, kq = lane >> 4;
#pragma unroll
  for (int pt = 0; pt < 2; ++pt) {
    char* b = smem + pt * BUFS;
    stage_tile<64, 2, 256>(Ag, 1024, pt * 64, b, tid);
    stage_tile<64, 2, 256>(Bseg0, 1024, pt * 64, b + 8192, tid);
    stage_tile<64, 2, 256>(Bseg1, 1024, pt * 64, b + 16384, tid);
    stage_tile<64, 2, 256>(Bseg2, 1024, pt * 64, b + 24576, tid);
  }
  int cur = 0;
  for (int t = 0; t < 16; ++t) {
    if (t + 1 < 16) wait_vm<8>(); else wait_vm<0>();
    __builtin_amdgcn_s_barrier();
    if (t + 2 < 16) {
      int nbid = cur + 2; if (nbid >= 3) nbid -= 3;
      char* nb = smem + nbid * BUFS;
      stage_tile<64, 2, 256>(Ag, 1024, (t + 2) << 6, nb, tid);
      stage_tile<64, 2, 256>(Bseg0, 1024, (t + 2) << 6, nb + 8192, tid);
      stage_tile<64, 2, 256>(Bseg1, 1024, (t + 2) << 6, nb + 16384, tid);
      stage_tile<64, 2, 256>(Bseg2, 1024, (t + 2) << 6, nb + 24576, tid);
    }
    const char* la = smem + cur * BUFS;
#pragma unroll
    for (int kk = 0; kk < 2; ++kk) {
      int k8 = kk * 4 + kq;
      bf16x8 af[2], bfr[6];
#pragma unroll
      for (int m = 0; m < 2; m++) af[m] = ld_frag<64>(la, wr * 32 + m * 16 + rA, k8);
#pragma unroll
      for (int n = 0; n < 6; n++) {
        int cidx = wc * 96 + n * 16 + rA;                  // 0..191
        bfr[n] = ld_frag<64>(la + 8192 + (cidx >> 6) * 8192, cidx & 63, k8);
      }
#pragma unroll
      for (int m = 0; m < 2; m++)
#pragma unroll
        for (int n = 0; n < 6; n++)
          acc[m][n] = __builtin_amdgcn_mfma_f32_16x16x32_bf16(af[m], bfr[n], acc[m][n], 0, 0, 0);
    }
    cur = (cur + 1 == 3) ? 0 : cur + 1;
  }
  __syncthreads();   // slab region aliases buf0: drain all reads before overwrite
  unsigned short* slab = (unsigned short*)smem;
  float* Sb = (float*)(smem + 64 * SLABW * 2 + wid * 512);   // per-wave [2][8][8] f32
#pragma unroll
  for (int m = 0; m < 2; m++)
#pragma unroll
    for (int n = 0; n < 6; n++) {
      int r = wr * 32 + m * 16 + (kq << 2);
      int c = wc * 96 + n * 16 + rA;
#pragma unroll
      for (int j = 0; j < 4; j++) slab[(size_t)(r + j) * SLABW + c] = f2bf(acc[m][n][j]);
    }
  __syncthreads();
  {
#pragma unroll
    for (int e = 0; e < 2; ++e) {
      int idx = e * 64 + lane;
      int bl = idx >> 6;
      int i = (idx >> 3) & 7, j = idx & 7;
      int rb8 = wid * 16 + bl * 8;
      const u16x8* qrow = (const u16x8*)(slab + (size_t)(rb8 + i) * SLABW);
      const u16x8* krow = (const u16x8*)(slab + (size_t)(rb8 + j) * SLABW + 64);
      float s = 0.f;
#pragma unroll
      for (int q8 = 0; q8 < 8; ++q8) {
        u16x8 qv = qrow[q8], kv = krow[q8];
#pragma unroll
        for (int u = 0; u < 8; ++u) s = fmaf(bf2f(qv[u]), bf2f(kv[u]), s);
      }
      Sb[bl * 64 + i * 8 + j] = s * 0.125f;
    }
    if (lane < 16) {
      float4 r0 = ((const float4*)(Sb + lane * 8))[0];
      float4 r1 = ((const float4*)(Sb + lane * 8))[1];
      float mx = fmaxf(fmaxf(fmaxf(r0.x, r0.y), fmaxf(r0.z, r0.w)),
                       fmaxf(fmaxf(r1.x, r1.y), fmaxf(r1.z, r1.w)));
      float e0 = expf(r0.x - mx), e1 = expf(r0.y - mx), e2 = expf(r0.z - mx), e3 = expf(r0.w - mx);
      float e4_ = expf(r1.x - mx), e5 = expf(r1.y - mx), e6 = expf(r1.z - mx), e7 = expf(r1.w - mx);
      float inv = 1.0f / (e0 + e1 + e2 + e3 + e4_ + e5 + e6 + e7);
      ((float4*)(Sb + lane * 8))[0] = make_float4(e0 * inv, e1 * inv, e2 * inv, e3 * inv);
      ((float4*)(Sb + lane * 8))[1] = make_float4(e4_ * inv, e5 * inv, e6 * inv, e7 * inv);
    }
#pragma unroll
    for (int bl = 0; bl < 2; ++bl) {
      int rb8 = wid * 16 + bl * 8;
      float vreg[8];
#pragma unroll
      for (int jj = 0; jj < 8; ++jj) vreg[jj] = bf2f(slab[(size_t)(rb8 + jj) * SLABW + 128 + lane]);
      int browg = (my * 8 + wid * 2 + bl) * 8;
#pragma unroll
      for (int i = 0; i < 8; ++i) {
        float4 p0 = ((const float4*)(Sb + (bl * 64 + i * 8)))[0];
        float4 p1 = ((const float4*)(Sb + (bl * 64 + i * 8)))[1];
        float o = p0.x * vreg[0] + p0.y * vreg[1] + p0.z * vreg[2] + p0.w * vreg[3] +
                  p1.x * vreg[4] + p1.y * vreg[5] + p1.z * vreg[6] + p1.w * vreg[7];
        obuf[(size_t)(browg + i) * 512 + hh * 64 + lane] = f2bf(o);
      }
    }
  }
}

// ---------- front1: wcast(img) + crop ----------
__global__ __launch_bounds__(256) void front1(
    const float* __restrict__ x, const float* __restrict__ tr,
    const float* __restrict__ w_img, const float* __restrict__ w_qkv, const float* __restrict__ w_o,
    const float* __restrict__ w_ff1, const float* __restrict__ w_ff2, const float* __restrict__ w_cls,
    unsigned short* BT_img, unsigned short* BT_qkv, unsigned short* BT_o,
    unsigned short* BT_ff1, unsigned short* BT_ff2, unsigned short* BT_cls,
    unsigned short* feats) {
  __shared__ __align__(16) char smem[16640];
  int bid = blockIdx.x;
  int tid = threadIdx.x;
  if (bid < 1024) {
    wcast_tile(smem, bid, w_img, w_qkv, w_o, w_ff1, w_ff2, w_cls,
               BT_img, BT_qkv, BT_o, BT_ff1, BT_ff2, BT_cls);
  } else {
    int b = bid - 1024;
    int* xi = (int*)smem;
    int* yi = xi + 64;
    float px = tr[b * 4 + 0], py = tr[b * 4 + 1], zx = tr[b * 4 + 2], zy = tr[b * 4 + 3];
    float x1 = __fmul_rn(px, 448.0f);
    float y1 = __fmul_rn(py, 448.0f);
    float xs = fminf(__fsub_rn(512.0f, x1), __fadd_rn(__fmul_rn(zx, 448.0f), 64.0f));
    float ys = fminf(__fsub_rn(512.0f, y1), __fadd_rn(__fmul_rn(zy, 448.0f), 64.0f));
    if (tid < 64) {
      float u = __fmul_rn(__fmul_rn((float)tid, 0.015625f), xs);
      int v = (int)(__fadd_rn(floorf(u), x1));
      xi[tid] = min(max(v, 0), 511);
    } else if (tid < 128) {
      int tt = tid - 64;
      float u = __fmul_rn(__fmul_rn((float)tt, 0.015625f), ys);
      int v = (int)(__fadd_rn(floorf(u), y1));
      yi[tt] = min(max(v, 0), 511);
    }
    __syncthreads();
    const float* img = x + (size_t)b * 262144;
    for (int p = tid; p < 4096; p += 256) {
      int i = p >> 6, j = p & 63;
      float val = img[xi[i] * 512 + yi[j]] * 128.0f;
      feats[(size_t)b * 4096 + p] = f2bf(val);
    }
  }
}

// ---------- k_img: imgGEMM split-K x8 (XCD-clustered) + wcast rest + zinit ----------
__global__ __launch_bounds__(256) void k_img(
    const unsigned short* __restrict__ feats, const unsigned short* __restrict__ BT_img,
    float* __restrict__ part, const float* __restrict__ hist, unsigned short* __restrict__ z,
    const float* __restrict__ w_img, const float* __restrict__ w_qkv, const float* __restrict__ w_o,
    const float* __restrict__ w_ff1, const float* __restrict__ w_ff2, const float* __restrict__ w_cls,
    unsigned short* BT_img_d, unsigned short* BT_qkv, unsigned short* BT_o,
    unsigned short* BT_ff1, unsigned short* BT_ff2, unsigned short* BT_cls) {
  __shared__ __align__(16) char smem[73728];
  int bid = blockIdx.x;
  if (bid < 256) {
    int xslot = bid & 7, rem = bid >> 3;
    int nx = rem & 15, chi = rem >> 4;
    int c = xslot + 8 * chi;
    int sk = c >> 1, my = c & 1;
    gemm_tile<64, 0, 0, false, 64, 256>(smem, feats, 4096, BT_img, 4096, 512,
                                        nullptr, nullptr, part + (size_t)sk * 262144, nullptr,
                                        1024, 1024, my * 128, nx * 64, sk * 512);
  } else if (bid < 6400) {
    wcast_tile(smem, 1024 + bid - 256, w_img, w_qkv, w_o, w_ff1, w_ff2, w_cls,
               BT_img_d, BT_qkv, BT_o, BT_ff1, BT_ff2, BT_cls);
  } else {
    int idx = (bid - 6400) * 256 + threadIdx.x;    // 1792 blocks * 256 = 458752
    int off = idx * 4;
    int b = off / 7168;
    int r = off - b * 7168;
    int i = r >> 10, c = r & 1023;
    float4 v = *(const float4*)(hist + (size_t)(i + 1) * 262144 + (size_t)b * 1024 + c);
    u16x4 o;
    o.x = f2bf(v.x); o.y = f2bf(v.y); o.z = f2bf(v.z); o.w = f2bf(v.w);
    *(u16x4*)(z + (size_t)b * 8192 + i * 1024 + c) = o;
  }
}

// ---------- LayerNorm one row from bf16 z (wave-level helper) ----------
__device__ __forceinline__ void ln_row(const unsigned short* __restrict__ z, int row,
                                       const float* __restrict__ sc, const float* __restrict__ bi,
                                       unsigned short* __restrict__ h) {
  int lane = threadIdx.x & 63;
  const unsigned short* zr = z + (size_t)row * 1024;
  float vf[16];
  float s = 0.f, q = 0.f;
#pragma unroll
  for (int i = 0; i < 2; i++) {
    u16x8 v = *(const u16x8*)(zr + lane * 8 + i * 512);
#pragma unroll
    for (int u = 0; u < 8; u++) {
      float f = bf2f(v[u]);
      vf[i * 8 + u] = f;
      s += f; q += f * f;
    }
  }
#pragma unroll
  for (int off = 32; off; off >>= 1) { s += __shfl_xor(s, off); q += __shfl_xor(q, off); }
  float mean = s * (1.0f / 1024.0f);
  float var = q * (1.0f / 1024.0f) - mean * mean;
  float rstd = rsqrtf(var + 1e-5f);
#pragma unroll
  for (int i = 0; i < 2; i++) {
    int c = lane * 8 + i * 512;
    float4 s0 = *(const float4*)(sc + c);
    float4 s1 = *(const float4*)(sc + c + 4);
    float4 b0 = *(const float4*)(bi + c);
    float4 b1 = *(const float4*)(bi + c + 4);
    u16x8 o;
    o[0] = f2bf((vf[i * 8 + 0] - mean) * rstd * s0.x + b0.x);
    o[1] = f2bf((vf[i * 8 + 1] - mean) * rstd * s0.y + b0.y);
    o[2] = f2bf((vf[i * 8 + 2] - mean) * rstd * s0.z + b0.z);
    o[3] = f2bf((vf[i * 8 + 3] - mean) * rstd * s0.w + b0.w);
    o[4] = f2bf((vf[i * 8 + 4] - mean) * rstd * s1.x + b1.x);
    o[5] = f2bf((vf[i * 8 + 5] - mean) * rstd * s1.y + b1.y);
    o[6] = f2bf((vf[i * 8 + 6] - mean) * rstd * s1.z + b1.z);
    o[7] = f2bf((vf[i * 8 + 7] - mean) * rstd * s1.w + b1.w);
    *(u16x8*)(h + (size_t)row * 1024 + c) = o;
  }
}

// ---------- imgred + ln1(layer 0): block m handles batch m ----------
__global__ __launch_bounds__(256) void imgred_ln(
    const float* __restrict__ part, const float* __restrict__ b_img,
    unsigned short* __restrict__ z,
    const float* __restrict__ sc, const float* __restrict__ bi,
    unsigned short* __restrict__ h) {
  __shared__ float ws[8];
  int m = blockIdx.x, tid = threadIdx.x;
  int lane = tid & 63, wid = tid >> 6;
  int c = tid * 4;
  float4 a = {0.f, 0.f, 0.f, 0.f};
  for (int p = 0; p < 8; ++p) {
    float4 v = *(const float4*)(part + (size_t)p * 262144 + m * 1024 + c);
    a.x += v.x; a.y += v.y; a.z += v.z; a.w += v.w;
  }
  float4 bv = *(const float4*)(b_img + c);
  a.x += bv.x; a.y += bv.y; a.z += bv.z; a.w += bv.w;
  u16x4 zo;
  zo.x = f2bf(a.x); zo.y = f2bf(a.y); zo.z = f2bf(a.z); zo.w = f2bf(a.w);
  *(u16x4*)(z + (size_t)m * 8192 + 7168 + c) = zo;
  float s = a.x + a.y + a.z + a.w;
  float q = a.x * a.x + a.y * a.y + a.z * a.z + a.w * a.w;
#pragma unroll
  for (int off = 32; off; off >>= 1) { s += __shfl_xor(s, off); q += __shfl_xor(q, off); }
  if (lane == 0) { ws[wid * 2] = s; ws[wid * 2 + 1] = q; }
  __syncthreads();
  float S4 = ws[0] + ws[2] + ws[4] + ws[6];
  float Q4 = ws[1] + ws[3] + ws[5] + ws[7];
  float mean = S4 * (1.0f / 1024.0f);
  float var = Q4 * (1.0f / 1024.0f) - mean * mean;
  float rstd = rsqrtf(var + 1e-5f);
  float4 sv = *(const float4*)(sc + c);
  float4 bb = *(const float4*)(bi + c);
  u16x4 o;
  o.x = f2bf((a.x - mean) * rstd * sv.x + bb.x);
  o.y = f2bf((a.y - mean) * rstd * sv.y + bb.y);
  o.z = f2bf((a.z - mean) * rstd * sv.z + bb.z);
  o.w = f2bf((a.w - mean) * rstd * sv.w + bb.w);
  *(u16x4*)(h + (size_t)(m * 8 + 7) * 1024 + c) = o;
#pragma unroll
  for (int rr = 0; rr < 2; ++rr) {
    int r = wid * 2 + rr;
    if (r < 7) ln_row(z, m * 8 + r, sc, bi, h);
  }
}

// ---------- LayerNorm kernel (wave per row) ----------
__global__ __launch_bounds__(256) void ln_kernel(const unsigned short* __restrict__ z,
                                                 const float* __restrict__ sc,
                                                 const float* __restrict__ bi,
                                                 unsigned short* __restrict__ h) {
  int row = blockIdx.x * 4 + (threadIdx.x >> 6);
  ln_row(z, row, sc, bi, h);
}

// ---------- standalone GEMM wrapper: 128 threads, 2 waves, XCD-clustered by my ----------
template <int TN, int ACT, int OMODE, bool RES, int BK>
__global__ __launch_bounds__(128) void gemm_k(
    const unsigned short* __restrict__ A, int lda,
    const unsigned short* __restrict__ BT, int ldb, int Kloop,
    const float* __restrict__ bias, const unsigned short* __restrict__ res,
    float* __restrict__ outF, unsigned short* __restrict__ outB,
    int ldC, int Nstore) {
  constexpr int BUFS = (128 + TN) * BK * 2;
  __shared__ __align__(16) char smem[3 * BUFS];
  int p = blockIdx.x;
  int xslot = p & 7, rem = p >> 3;
  int nx = rem & 15;
  int my = xslot + 8 * (rem >> 4);     // 0..15
  gemm_tile<TN, ACT, OMODE, RES, BK, 128>(smem, A, lda, BT, ldb, Kloop, bias, res, outF, outB,
                                          ldC, Nstore, my * 128, nx * TN, 0);
}

// ---------- k_cls: cls GEMM split-K x8 (XCD-clustered) + transform head ----------
__global__ __launch_bounds__(256) void k_cls(
    const unsigned short* __restrict__ z, const unsigned short* __restrict__ BT_cls,
    float* __restrict__ part, const float* __restrict__ w_tr,
    const float* __restrict__ b_tr, float* __restrict__ outF) {
  __shared__ __align__(16) char smem[73728];
  int bid = blockIdx.x;
  int tid = threadIdx.x;
  if (bid < 256) {
    int xslot = bid & 7, rem = bid >> 3;
    int nx = rem & 15, chi = rem >> 4;
    int c = xslot + 8 * chi;
    int sk = c >> 1, my = c & 1;
    gemm_tile<64, 0, 0, false, 64, 256>(smem, z, 8192, BT_cls, 8192, 1024,
                                        nullptr, nullptr, part + (size_t)sk * 262144, nullptr,
                                        1024, 1024, my * 128, nx * 64, sk * 1024);
  } else {
    int m = bid - 256;
    const unsigned short* row = z + (size_t)m * 8192;
    float a0 = 0.f, a1 = 0.f, a2 = 0.f, a3 = 0.f;
    for (int k = tid; k < 8192; k += 256) {
      float xv = bf2f(row[k]);
      const float* wr = w_tr + (size_t)k * 4;
      a0 += xv * wr[0]; a1 += xv * wr[1]; a2 += xv * wr[2]; a3 += xv * wr[3];
    }
    float (*red)[4] = (float (*)[4])smem;
    red[tid][0] = a0; red[tid][1] = a1; red[tid][2] = a2; red[tid][3] = a3;
    __syncthreads();
    for (int s = 128; s > 0; s >>= 1) {
      if (tid < s) {
#pragma unroll
        for (int o = 0; o < 4; o++) red[tid][o] += red[tid + s][o];
      }
      __syncthreads();
    }
    if (tid < 4) {
      float v = red[0][tid] + b_tr[tid];
      outF[256000 + m * 4 + tid] = 1.0f / (1.0f + expf(-v));
    }
  }
}

// ---------- cls reduce -> outF[:, :1000] ----------
__global__ __launch_bounds__(256) void clsred(const float* __restrict__ part,
                                              const float* __restrict__ b_cls,
                                              float* __restrict__ outF) {
  int m = blockIdx.x, c = threadIdx.x * 4;
  float4 a = {0.f, 0.f, 0.f, 0.f};
  for (int p = 0; p < 8; ++p) {
    float4 v = *(const float4*)(part + (size_t)p * 262144 + m * 1024 + c);
    a.x += v.x; a.y += v.y; a.z += v.z; a.w += v.w;
  }
  if (c >= 1000) return;
  float* drow = outF + (size_t)m * 1000;
  float vals[4] = {a.x, a.y, a.z, a.w};
  if (c + 3 < 1000) {
    *(float4*)(drow + c) = make_float4(vals[0] + b_cls[c], vals[1] + b_cls[c + 1],
                                       vals[2] + b_cls[c + 2], vals[3] + b_cls[c + 3]);
  } else {
    for (int j = 0; j < 4 && c + j < 1000; ++j) drow[c + j] = vals[j] + b_cls[c + j];
  }
}

// ---------- launch ----------
extern "C" void kernel_launch(void* const* d_in, const int* in_sizes, int n_in,
                              void* d_out, int out_size, void* d_ws, size_t ws_size,
                              hipStream_t stream) {
  const float* x      = (const float*)d_in[0];
  const float* tr     = (const float*)d_in[1];
  const float* hist   = (const float*)d_in[2];
  const float* w_img  = (const float*)d_in[3];
  const float* b_img  = (const float*)d_in[4];
  const float* ln1_s  = (const float*)d_in[5];
  const float* ln1_b  = (const float*)d_in[6];
  const float* w_qkv  = (const float*)d_in[7];
  const float* w_o    = (const float*)d_in[8];
  const float* b_o    = (const float*)d_in[9];
  const float* ln2_s  = (const float*)d_in[10];
  const float* ln2_b  = (const float*)d_in[11];
  const float* w_ff1  = (const float*)d_in[12];
  const float* b_ff1  = (const float*)d_in[13];
  const float* w_ff2  = (const float*)d_in[14];
  const float* b_ff2  = (const float*)d_in[15];
  const float* w_cls  = (const float*)d_in[16];
  const float* b_cls  = (const float*)d_in[17];
  const float* w_tr   = (const float*)d_in[18];
  const float* b_tr   = (const float*)d_in[19];
  float* outF = (float*)d_out;

  char* w = (char*)d_ws;
  auto alloc = [&](size_t bytes) { char* p = w; w += (bytes + 255) & ~(size_t)255; return p; };
  unsigned short* BT_img = (unsigned short*)alloc((size_t)1024 * 4096 * 2);
  unsigned short* BT_qkv = (unsigned short*)alloc((size_t)4 * 1536 * 1024 * 2);
  unsigned short* BT_o   = (unsigned short*)alloc((size_t)4 * 1024 * 512 * 2);
  unsigned short* BT_ff1 = (unsigned short*)alloc((size_t)4 * 1024 * 1024 * 2);
  unsigned short* BT_ff2 = (unsigned short*)alloc((size_t)4 * 1024 * 1024 * 2);
  unsigned short* BT_cls = (unsigned short*)alloc((size_t)1024 * 8192 * 2);
  unsigned short* feats  = (unsigned short*)alloc((size_t)256 * 4096 * 2);
  unsigned short* z      = (unsigned short*)alloc((size_t)2048 * 1024 * 2);   // bf16 residual stream
  unsigned short* h      = (unsigned short*)alloc((size_t)2048 * 1024 * 2);
  unsigned short* obuf   = (unsigned short*)alloc((size_t)2048 * 512 * 2);
  unsigned short* g      = (unsigned short*)alloc((size_t)2048 * 1024 * 2);
  float*          part   = (float*)alloc((size_t)8 * 256 * 1024 * 4);
  if ((size_t)(w - (char*)d_ws) > ws_size) return;

  front1<<<1280, 256, 0, stream>>>(x, tr, w_img, w_qkv, w_o, w_ff1, w_ff2, w_cls,
                                   BT_img, BT_qkv, BT_o, BT_ff1, BT_ff2, BT_cls, feats);
  k_img<<<8192, 256, 0, stream>>>(feats, BT_img, part, hist, z,
                                  w_img, w_qkv, w_o, w_ff1, w_ff2, w_cls,
                                  BT_img, BT_qkv, BT_o, BT_ff1, BT_ff2, BT_cls);
  imgred_ln<<<256, 256, 0, stream>>>(part, b_img, z, ln1_s, ln1_b, h);

  for (int i = 0; i < 4; ++i) {
    const unsigned short* Wq = BT_qkv + (size_t)i * 1536 * 1024;
    const unsigned short* Wo = BT_o   + (size_t)i * 1024 * 512;
    const unsigned short* W1 = BT_ff1 + (size_t)i * 1024 * 1024;
    const unsigned short* W2 = BT_ff2 + (size_t)i * 1024 * 1024;
    if (i > 0)
      ln_kernel<<<512, 256, 0, stream>>>(z, ln1_s + i * 1024, ln1_b + i * 1024, h);
    qkvattn<<<256, 256, 0, stream>>>(h, Wq, obuf);
    gemm_k<64, 0, 1, true, 64><<<256, 128, 0, stream>>>(
        obuf, 512, Wo, 512, 512, b_o + i * 1024, z, nullptr, z, 1024, 1024);
    ln_kernel<<<512, 256, 0, stream>>>(z, ln2_s + i * 1024, ln2_b + i * 1024, h);
    gemm_k<64, 1, 1, false, 64><<<256, 128, 0, stream>>>(
        h, 1024, W1, 1024, 1024, b_ff1 + i * 1024, nullptr, nullptr, g, 1024, 1024);
    gemm_k<64, 0, 1, true, 64><<<256, 128, 0, stream>>>(
        g, 1024, W2, 1024, 1024, b_ff2 + i * 1024, z, nullptr, z, 1024, 1024);
  }

  k_cls<<<512, 256, 0, stream>>>(z, BT_cls, part, w_tr, b_tr, outF);
  clsred<<<256, 256, 0, stream>>>(part, b_cls, outF);
}

// Round 13
// 293.239 us; speedup vs baseline: 1.2359x; 1.2359x over previous
//
#include <hip/hip_runtime.h>
#include <cstdint>
#include <cstddef>

// ---------- types ----------
typedef __attribute__((ext_vector_type(8))) __bf16 bf16x8;
typedef __attribute__((ext_vector_type(8))) unsigned short u16x8;
typedef __attribute__((ext_vector_type(4))) float f32x4;
typedef __attribute__((ext_vector_type(4))) unsigned short u16x4;

__device__ __forceinline__ unsigned short f2bf(float f) {
  unsigned int u = __builtin_bit_cast(unsigned int, f);
  u += 0x7fffu + ((u >> 16) & 1u);           // RNE
  return (unsigned short)(u >> 16);
}
__device__ __forceinline__ float bf2f(unsigned short u) {
  return __builtin_bit_cast(float, ((unsigned int)u) << 16);
}

// counted vmcnt waits (T4): literal immediates via if constexpr
template <int N> __device__ __forceinline__ void wait_vm() {
  if constexpr (N == 0)      asm volatile("s_waitcnt vmcnt(0)" ::: "memory");
  else if constexpr (N == 6) asm volatile("s_waitcnt vmcnt(6)" ::: "memory");
  else if constexpr (N == 8) asm volatile("s_waitcnt vmcnt(8)" ::: "memory");
  else                       asm volatile("s_waitcnt vmcnt(0)" ::: "memory");
}

// ---------- weight cast+transpose, one 64x64 tile (tile id in [0,7168)) ----------
__device__ void wcast_tile(char* smemc, int bid,
    const float* s_img, const float* s_qkv, const float* s_o,
    const float* s_ff1, const float* s_ff2, const float* s_cls,
    unsigned short* d_img, unsigned short* d_qkv, unsigned short* d_o,
    unsigned short* d_ff1, unsigned short* d_ff2, unsigned short* d_cls) {
  float (*tile)[65] = (float (*)[65])smemc;
  const float* src; unsigned short* dst; int K, N, Npad, rel;
  if (bid < 1024)       { src = s_img; dst = d_img; K = 4096; N = 1024; Npad = 1024; rel = bid; }
  else if (bid < 2560)  { rel = bid - 1024; int l = rel / 384; rel -= l * 384;
                          src = s_qkv + (size_t)l * 1024 * 1536; dst = d_qkv + (size_t)l * 1536 * 1024;
                          K = 1024; N = 1536; Npad = 1536; }
  else if (bid < 3072)  { rel = bid - 2560; int l = rel / 128; rel -= l * 128;
                          src = s_o   + (size_t)l * 512 * 1024;  dst = d_o   + (size_t)l * 1024 * 512;
                          K = 512;  N = 1024; Npad = 1024; }
  else if (bid < 4096)  { rel = bid - 3072; int l = rel / 256; rel -= l * 256;
                          src = s_ff1 + (size_t)l * 1024 * 1024; dst = d_ff1 + (size_t)l * 1024 * 1024;
                          K = 1024; N = 1024; Npad = 1024; }
  else if (bid < 5120)  { rel = bid - 4096; int l = rel / 256; rel -= l * 256;
                          src = s_ff2 + (size_t)l * 1024 * 1024; dst = d_ff2 + (size_t)l * 1024 * 1024;
                          K = 1024; N = 1024; Npad = 1024; }
  else                  { rel = bid - 5120; src = s_cls; dst = d_cls; K = 8192; N = 1000; Npad = 1024; }
  int tilesX = Npad >> 6;
  int nx = rel % tilesX, ky = rel / tilesX;
  int n0 = nx << 6, k0 = ky << 6;
  int t = threadIdx.x;
#pragma unroll
  for (int i = 0; i < 4; ++i) {
    int slot = t + i * 256;
    int kk = slot >> 4, cq = slot & 15;
    int n = n0 + cq * 4;
    float4 v;
    if (n + 3 < N) v = *(const float4*)(src + (size_t)(k0 + kk) * N + n);
    else {
      v.x = v.y = v.z = v.w = 0.0f;
      if (n < N)     v.x = src[(size_t)(k0 + kk) * N + n];
      if (n + 1 < N) v.y = src[(size_t)(k0 + kk) * N + n + 1];
      if (n + 2 < N) v.z = src[(size_t)(k0 + kk) * N + n + 2];
      if (n + 3 < N) v.w = src[(size_t)(k0 + kk) * N + n + 3];
    }
    tile[kk][cq * 4 + 0] = v.x;
    tile[kk][cq * 4 + 1] = v.y;
    tile[kk][cq * 4 + 2] = v.z;
    tile[kk][cq * 4 + 3] = v.w;
  }
  __syncthreads();
#pragma unroll
  for (int i = 0; i < 4; ++i) {
    int slot = t + i * 256;
    int n = slot >> 4, kq = slot & 15;
    u16x4 o;
    o.x = f2bf(tile[kq * 4 + 0][n]);
    o.y = f2bf(tile[kq * 4 + 1][n]);
    o.z = f2bf(tile[kq * 4 + 2][n]);
    o.w = f2bf(tile[kq * 4 + 3][n]);
    *(u16x4*)(dst + (size_t)(n0 + n) * K + k0 + kq * 4) = o;
  }
  __syncthreads();
}

// ---------- GEMM pieces (BK=64) ----------
template <int BK, int ITERS>
__device__ __forceinline__ void stage_tile(const unsigned short* __restrict__ g, int ld,
                                           int k0, char* lbase, int tid) {
  constexpr int CH = BK / 8;           // 16B chunks per row
#pragma unroll
  for (int it = 0; it < ITERS; ++it) {
    int c = tid + it * 256;
    int r = c / CH;
    int slot = c & (CH - 1);
    int gc = slot ^ (r & (CH - 1));    // pre-swizzled global source (m173 pattern)
    const unsigned short* src = g + (size_t)r * ld + (k0 + gc * 8);
    char* dst = lbase + c * 16;        // linear LDS dest
    __builtin_amdgcn_global_load_lds((__attribute__((address_space(1))) void*)src,
                                     (__attribute__((address_space(3))) void*)dst, 16, 0, 0);
  }
}

template <int BK>
__device__ __forceinline__ bf16x8 ld_frag(const char* base, int row, int k8) {
  constexpr int CH = BK / 8;
  int off = row * (BK * 2) + ((k8 ^ (row & (CH - 1))) << 4);   // XOR swizzle (G4)
  return *(const bf16x8*)(base + off);
}

// TM=128, TN=64: 4 waves, wave owns 32x64 (MR=2). OMODE: 0=f32 out, 1=bf16 out.
// 3-buffer pipelined K-loop: counted vmcnt + raw barriers (T3/T4-lite).
template <int TN, int ACT, int OMODE, bool RES, int BK>
__device__ void gemm_tile(char* smem,
    const unsigned short* __restrict__ A, int lda,
    const unsigned short* __restrict__ BT, int ldb, int Kloop,
    const float* __restrict__ bias, const unsigned short* __restrict__ res,
    float* __restrict__ outF, unsigned short* __restrict__ outB,
    int ldC, int Nstore, int m0, int n0, int koff) {
  constexpr int MR = (TN == 64) ? 2 : 4;
  constexpr int ABYTES = 128 * BK * 2;
  constexpr int BUFS = (128 + TN) * BK * 2;
  constexpr int AITERS = BK / 16;
  constexpr int BITERS = TN * BK / 2048;
  constexpr int VM = AITERS + BITERS;        // VMEM instrs/thread/tile
  const int tid = threadIdx.x;
  const int lane = tid & 63;
  const int wid = tid >> 6;
  const int rowbase = (TN == 64) ? wid * 32 : (wid >> 1) * 64;
  const int colbase = (TN == 64) ? 0 : (wid & 1) * 64;
  const unsigned short* Ag = A + (size_t)m0 * lda + koff;
  const unsigned short* Bg = BT + (size_t)n0 * ldb + koff;
  f32x4 acc[MR][4];
#pragma unroll
  for (int m = 0; m < MR; m++)
#pragma unroll
    for (int n = 0; n < 4; n++) acc[m][n] = 0.f;
  const int nt = Kloop / BK;
  // prologue: prefetch tiles 0 and 1
  stage_tile<BK, AITERS>(Ag, lda, 0, smem, tid);
  stage_tile<BK, BITERS>(Bg, ldb, 0, smem + ABYTES, tid);
  stage_tile<BK, AITERS>(Ag, lda, BK, smem + BUFS, tid);
  stage_tile<BK, BITERS>(Bg, ldb, BK, smem + BUFS + ABYTES, tid);
  int cur = 0;
  const int rA = lane & 15, kq = lane >> 4;
  for (int t = 0; t < nt; ++t) {
    if (t + 1 < nt) wait_vm<VM>(); else wait_vm<0>();   // tile t landed; t+1 in flight
    __builtin_amdgcn_s_barrier();                       // all waves: t ready, t-1 reads done
    if (t + 2 < nt) {
      int nb = cur + 2; if (nb >= 3) nb -= 3;
      stage_tile<BK, AITERS>(Ag, lda, (t + 2) * BK, smem + nb * BUFS, tid);
      stage_tile<BK, BITERS>(Bg, ldb, (t + 2) * BK, smem + nb * BUFS + ABYTES, tid);
    }
    const char* la = smem + cur * BUFS;
    const char* lb = la + ABYTES;
#pragma unroll
    for (int kk = 0; kk < BK / 32; ++kk) {
      int k8 = kk * 4 + kq;
      bf16x8 af[MR], bfr[4];
#pragma unroll
      for (int m = 0; m < MR; m++) af[m] = ld_frag<BK>(la, rowbase + m * 16 + rA, k8);
#pragma unroll
      for (int n = 0; n < 4; n++) bfr[n] = ld_frag<BK>(lb, colbase + n * 16 + rA, k8);
#pragma unroll
      for (int m = 0; m < MR; m++)
#pragma unroll
        for (int n = 0; n < 4; n++)
          acc[m][n] = __builtin_amdgcn_mfma_f32_16x16x32_bf16(af[m], bfr[n], acc[m][n], 0, 0, 0);
    }
    cur = (cur + 1 == 3) ? 0 : cur + 1;
  }
  const int rb = m0 + rowbase + (kq << 2);
  const int cb = n0 + colbase + rA;
#pragma unroll
  for (int m = 0; m < MR; m++)
#pragma unroll
    for (int n = 0; n < 4; n++) {
      int cg = cb + n * 16;
      if (cg >= Nstore) continue;
      float bv = bias ? bias[cg] : 0.0f;
#pragma unroll
      for (int j = 0; j < 4; j++) {
        int rg = rb + m * 16 + j;
        float v = acc[m][n][j] + bv;
        if (RES) v += bf2f(res[(size_t)rg * ldC + cg]);
        if (ACT == 1) v = 0.5f * v * (1.0f + erff(v * 0.70710678118654752f));
        if (OMODE == 0) {
          outF[(size_t)rg * ldC + cg] = v;
        } else {
          outB[(size_t)rg * ldC + cg] = f2bf(v);
        }
      }
    }
}

// ---------- fused qkv GEMM + attention, 64-row tiles, XCD-clustered, pipelined ----------
#define SLABW 200   // slab stride in u16: 400B, 16B-aligned, bank-shift 4 per row
__global__ __launch_bounds__(256) void qkvattn(
    const unsigned short* __restrict__ h,      // [2048][1024] bf16
    const unsigned short* __restrict__ BTq,    // [1536][1024] bf16 (layer slice)
    unsigned short* __restrict__ obuf) {       // [2048][512] bf16
  __shared__ __align__(16) char smem[98304];   // 3 x (A 8KB + B 24KB)
  const int tid = threadIdx.x, lane = tid & 63, wid = tid >> 6;
  const int p = blockIdx.x;
  const int xslot = p & 7, rem = p >> 3;
  const int hh = rem & 7;
  const int my = xslot + 8 * (rem >> 3);      // 0..31
  const int m0 = my << 6;
  const int wr = wid >> 1, wc = wid & 1;
  const unsigned short* Ag = h + (size_t)m0 * 1024;
  const unsigned short* Bseg0 = BTq + (size_t)(hh * 64) * 1024;
  const unsigned short* Bseg1 = BTq + (size_t)(512 + hh * 64) * 1024;
  const unsigned short* Bseg2 = BTq + (size_t)(1024 + hh * 64) * 1024;
  constexpr int BUFS = 32768;
  f32x4 acc[2][6];
#pragma unroll
  for (int m = 0; m < 2; m++)
#pragma unroll
    for (int n = 0; n < 6; n++) acc[m][n] = 0.f;
  const int rA = lane & 15, kq = lane >> 4;
#pragma unroll
  for (int pt = 0; pt < 2; ++pt) {
    char* b = smem + pt * BUFS;
    stage_tile<64, 2>(Ag, 1024, pt * 64, b, tid);
    stage_tile<64, 2>(Bseg0, 1024, pt * 64, b + 8192, tid);
    stage_tile<64, 2>(Bseg1, 1024, pt * 64, b + 16384, tid);
    stage_tile<64, 2>(Bseg2, 1024, pt * 64, b + 24576, tid);
  }
  int cur = 0;
  for (int t = 0; t < 16; ++t) {
    if (t + 1 < 16) wait_vm<8>(); else wait_vm<0>();
    __builtin_amdgcn_s_barrier();
    if (t + 2 < 16) {
      int nbid = cur + 2; if (nbid >= 3) nbid -= 3;
      char* nb = smem + nbid * BUFS;
      stage_tile<64, 2>(Ag, 1024, (t + 2) << 6, nb, tid);
      stage_tile<64, 2>(Bseg0, 1024, (t + 2) << 6, nb + 8192, tid);
      stage_tile<64, 2>(Bseg1, 1024, (t + 2) << 6, nb + 16384, tid);
      stage_tile<64, 2>(Bseg2, 1024, (t + 2) << 6, nb + 24576, tid);
    }
    const char* la = smem + cur * BUFS;
#pragma unroll
    for (int kk = 0; kk < 2; ++kk) {
      int k8 = kk * 4 + kq;
      bf16x8 af[2], bfr[6];
#pragma unroll
      for (int m = 0; m < 2; m++) af[m] = ld_frag<64>(la, wr * 32 + m * 16 + rA, k8);
#pragma unroll
      for (int n = 0; n < 6; n++) {
        int cidx = wc * 96 + n * 16 + rA;                  // 0..191
        bfr[n] = ld_frag<64>(la + 8192 + (cidx >> 6) * 8192, cidx & 63, k8);
      }
#pragma unroll
      for (int m = 0; m < 2; m++)
#pragma unroll
        for (int n = 0; n < 6; n++)
          acc[m][n] = __builtin_amdgcn_mfma_f32_16x16x32_bf16(af[m], bfr[n], acc[m][n], 0, 0, 0);
    }
    cur = (cur + 1 == 3) ? 0 : cur + 1;
  }
  __syncthreads();   // slab region aliases buf0: drain all reads before overwrite
  unsigned short* slab = (unsigned short*)smem;
  float* Sb = (float*)(smem + 64 * SLABW * 2 + wid * 512);   // per-wave [2][8][8] f32
#pragma unroll
  for (int m = 0; m < 2; m++)
#pragma unroll
    for (int n = 0; n < 6; n++) {
      int r = wr * 32 + m * 16 + (kq << 2);
      int c = wc * 96 + n * 16 + rA;
#pragma unroll
      for (int j = 0; j < 4; j++) slab[(size_t)(r + j) * SLABW + c] = f2bf(acc[m][n][j]);
    }
  __syncthreads();
  {
#pragma unroll
    for (int e = 0; e < 2; ++e) {
      int idx = e * 64 + lane;
      int bl = idx >> 6;
      int i = (idx >> 3) & 7, j = idx & 7;
      int rb8 = wid * 16 + bl * 8;
      const u16x8* qrow = (const u16x8*)(slab + (size_t)(rb8 + i) * SLABW);
      const u16x8* krow = (const u16x8*)(slab + (size_t)(rb8 + j) * SLABW + 64);
      float s = 0.f;
#pragma unroll
      for (int q8 = 0; q8 < 8; ++q8) {
        u16x8 qv = qrow[q8], kv = krow[q8];
#pragma unroll
        for (int u = 0; u < 8; ++u) s = fmaf(bf2f(qv[u]), bf2f(kv[u]), s);
      }
      Sb[bl * 64 + i * 8 + j] = s * 0.125f;
    }
    if (lane < 16) {
      float4 r0 = ((const float4*)(Sb + lane * 8))[0];
      float4 r1 = ((const float4*)(Sb + lane * 8))[1];
      float mx = fmaxf(fmaxf(fmaxf(r0.x, r0.y), fmaxf(r0.z, r0.w)),
                       fmaxf(fmaxf(r1.x, r1.y), fmaxf(r1.z, r1.w)));
      float e0 = expf(r0.x - mx), e1 = expf(r0.y - mx), e2 = expf(r0.z - mx), e3 = expf(r0.w - mx);
      float e4_ = expf(r1.x - mx), e5 = expf(r1.y - mx), e6 = expf(r1.z - mx), e7 = expf(r1.w - mx);
      float inv = 1.0f / (e0 + e1 + e2 + e3 + e4_ + e5 + e6 + e7);
      ((float4*)(Sb + lane * 8))[0] = make_float4(e0 * inv, e1 * inv, e2 * inv, e3 * inv);
      ((float4*)(Sb + lane * 8))[1] = make_float4(e4_ * inv, e5 * inv, e6 * inv, e7 * inv);
    }
#pragma unroll
    for (int bl = 0; bl < 2; ++bl) {
      int rb8 = wid * 16 + bl * 8;
      float vreg[8];
#pragma unroll
      for (int jj = 0; jj < 8; ++jj) vreg[jj] = bf2f(slab[(size_t)(rb8 + jj) * SLABW + 128 + lane]);
      int browg = (my * 8 + wid * 2 + bl) * 8;
#pragma unroll
      for (int i = 0; i < 8; ++i) {
        float4 p0 = ((const float4*)(Sb + (bl * 64 + i * 8)))[0];
        float4 p1 = ((const float4*)(Sb + (bl * 64 + i * 8)))[1];
        float o = p0.x * vreg[0] + p0.y * vreg[1] + p0.z * vreg[2] + p0.w * vreg[3] +
                  p1.x * vreg[4] + p1.y * vreg[5] + p1.z * vreg[6] + p1.w * vreg[7];
        obuf[(size_t)(browg + i) * 512 + hh * 64 + lane] = f2bf(o);
      }
    }
  }
}

// ---------- front1: wcast(img) + crop ----------
__global__ __launch_bounds__(256) void front1(
    const float* __restrict__ x, const float* __restrict__ tr,
    const float* __restrict__ w_img, const float* __restrict__ w_qkv, const float* __restrict__ w_o,
    const float* __restrict__ w_ff1, const float* __restrict__ w_ff2, const float* __restrict__ w_cls,
    unsigned short* BT_img, unsigned short* BT_qkv, unsigned short* BT_o,
    unsigned short* BT_ff1, unsigned short* BT_ff2, unsigned short* BT_cls,
    unsigned short* feats) {
  __shared__ __align__(16) char smem[16640];
  int bid = blockIdx.x;
  int tid = threadIdx.x;
  if (bid < 1024) {
    wcast_tile(smem, bid, w_img, w_qkv, w_o, w_ff1, w_ff2, w_cls,
               BT_img, BT_qkv, BT_o, BT_ff1, BT_ff2, BT_cls);
  } else {
    int b = bid - 1024;
    int* xi = (int*)smem;
    int* yi = xi + 64;
    float px = tr[b * 4 + 0], py = tr[b * 4 + 1], zx = tr[b * 4 + 2], zy = tr[b * 4 + 3];
    float x1 = __fmul_rn(px, 448.0f);
    float y1 = __fmul_rn(py, 448.0f);
    float xs = fminf(__fsub_rn(512.0f, x1), __fadd_rn(__fmul_rn(zx, 448.0f), 64.0f));
    float ys = fminf(__fsub_rn(512.0f, y1), __fadd_rn(__fmul_rn(zy, 448.0f), 64.0f));
    if (tid < 64) {
      float u = __fmul_rn(__fmul_rn((float)tid, 0.015625f), xs);
      int v = (int)(__fadd_rn(floorf(u), x1));
      xi[tid] = min(max(v, 0), 511);
    } else if (tid < 128) {
      int tt = tid - 64;
      float u = __fmul_rn(__fmul_rn((float)tt, 0.015625f), ys);
      int v = (int)(__fadd_rn(floorf(u), y1));
      yi[tt] = min(max(v, 0), 511);
    }
    __syncthreads();
    const float* img = x + (size_t)b * 262144;
    for (int p = tid; p < 4096; p += 256) {
      int i = p >> 6, j = p & 63;
      float val = img[xi[i] * 512 + yi[j]] * 128.0f;
      feats[(size_t)b * 4096 + p] = f2bf(val);
    }
  }
}

// ---------- k_img: imgGEMM split-K x8 (XCD-clustered) + wcast rest + zinit ----------
__global__ __launch_bounds__(256) void k_img(
    const unsigned short* __restrict__ feats, const unsigned short* __restrict__ BT_img,
    float* __restrict__ part, const float* __restrict__ hist, unsigned short* __restrict__ z,
    const float* __restrict__ w_img, const float* __restrict__ w_qkv, const float* __restrict__ w_o,
    const float* __restrict__ w_ff1, const float* __restrict__ w_ff2, const float* __restrict__ w_cls,
    unsigned short* BT_img_d, unsigned short* BT_qkv, unsigned short* BT_o,
    unsigned short* BT_ff1, unsigned short* BT_ff2, unsigned short* BT_cls) {
  __shared__ __align__(16) char smem[73728];
  int bid = blockIdx.x;
  if (bid < 256) {
    int xslot = bid & 7, rem = bid >> 3;
    int nx = rem & 15, chi = rem >> 4;
    int c = xslot + 8 * chi;
    int sk = c >> 1, my = c & 1;
    gemm_tile<64, 0, 0, false, 64>(smem, feats, 4096, BT_img, 4096, 512,
                                   nullptr, nullptr, part + (size_t)sk * 262144, nullptr,
                                   1024, 1024, my * 128, nx * 64, sk * 512);
  } else if (bid < 6400) {
    wcast_tile(smem, 1024 + bid - 256, w_img, w_qkv, w_o, w_ff1, w_ff2, w_cls,
               BT_img_d, BT_qkv, BT_o, BT_ff1, BT_ff2, BT_cls);
  } else {
    int idx = (bid - 6400) * 256 + threadIdx.x;    // 1792 blocks * 256 = 458752
    int off = idx * 4;
    int b = off / 7168;
    int r = off - b * 7168;
    int i = r >> 10, c = r & 1023;
    float4 v = *(const float4*)(hist + (size_t)(i + 1) * 262144 + (size_t)b * 1024 + c);
    u16x4 o;
    o.x = f2bf(v.x); o.y = f2bf(v.y); o.z = f2bf(v.z); o.w = f2bf(v.w);
    *(u16x4*)(z + (size_t)b * 8192 + i * 1024 + c) = o;
  }
}

// ---------- LayerNorm one row from bf16 z (wave-level helper) ----------
__device__ __forceinline__ void ln_row(const unsigned short* __restrict__ z, int row,
                                       const float* __restrict__ sc, const float* __restrict__ bi,
                                       unsigned short* __restrict__ h) {
  int lane = threadIdx.x & 63;
  const unsigned short* zr = z + (size_t)row * 1024;
  float vf[16];
  float s = 0.f, q = 0.f;
#pragma unroll
  for (int i = 0; i < 2; i++) {
    u16x8 v = *(const u16x8*)(zr + lane * 8 + i * 512);
#pragma unroll
    for (int u = 0; u < 8; u++) {
      float f = bf2f(v[u]);
      vf[i * 8 + u] = f;
      s += f; q += f * f;
    }
  }
#pragma unroll
  for (int off = 32; off; off >>= 1) { s += __shfl_xor(s, off); q += __shfl_xor(q, off); }
  float mean = s * (1.0f / 1024.0f);
  float var = q * (1.0f / 1024.0f) - mean * mean;
  float rstd = rsqrtf(var + 1e-5f);
#pragma unroll
  for (int i = 0; i < 2; i++) {
    int c = lane * 8 + i * 512;
    float4 s0 = *(const float4*)(sc + c);
    float4 s1 = *(const float4*)(sc + c + 4);
    float4 b0 = *(const float4*)(bi + c);
    float4 b1 = *(const float4*)(bi + c + 4);
    u16x8 o;
    o[0] = f2bf((vf[i * 8 + 0] - mean) * rstd * s0.x + b0.x);
    o[1] = f2bf((vf[i * 8 + 1] - mean) * rstd * s0.y + b0.y);
    o[2] = f2bf((vf[i * 8 + 2] - mean) * rstd * s0.z + b0.z);
    o[3] = f2bf((vf[i * 8 + 3] - mean) * rstd * s0.w + b0.w);
    o[4] = f2bf((vf[i * 8 + 4] - mean) * rstd * s1.x + b1.x);
    o[5] = f2bf((vf[i * 8 + 5] - mean) * rstd * s1.y + b1.y);
    o[6] = f2bf((vf[i * 8 + 6] - mean) * rstd * s1.z + b1.z);
    o[7] = f2bf((vf[i * 8 + 7] - mean) * rstd * s1.w + b1.w);
    *(u16x8*)(h + (size_t)row * 1024 + c) = o;
  }
}

// ---------- imgred + ln1(layer 0): block m handles batch m ----------
__global__ __launch_bounds__(256) void imgred_ln(
    const float* __restrict__ part, const float* __restrict__ b_img,
    unsigned short* __restrict__ z,
    const float* __restrict__ sc, const float* __restrict__ bi,
    unsigned short* __restrict__ h) {
  __shared__ float ws[8];
  int m = blockIdx.x, tid = threadIdx.x;
  int lane = tid & 63, wid = tid >> 6;
  int c = tid * 4;
  float4 a = {0.f, 0.f, 0.f, 0.f};
  for (int p = 0; p < 8; ++p) {
    float4 v = *(const float4*)(part + (size_t)p * 262144 + m * 1024 + c);
    a.x += v.x; a.y += v.y; a.z += v.z; a.w += v.w;
  }
  float4 bv = *(const float4*)(b_img + c);
  a.x += bv.x; a.y += bv.y; a.z += bv.z; a.w += bv.w;
  u16x4 zo;
  zo.x = f2bf(a.x); zo.y = f2bf(a.y); zo.z = f2bf(a.z); zo.w = f2bf(a.w);
  *(u16x4*)(z + (size_t)m * 8192 + 7168 + c) = zo;
  float s = a.x + a.y + a.z + a.w;
  float q = a.x * a.x + a.y * a.y + a.z * a.z + a.w * a.w;
#pragma unroll
  for (int off = 32; off; off >>= 1) { s += __shfl_xor(s, off); q += __shfl_xor(q, off); }
  if (lane == 0) { ws[wid * 2] = s; ws[wid * 2 + 1] = q; }
  __syncthreads();
  float S4 = ws[0] + ws[2] + ws[4] + ws[6];
  float Q4 = ws[1] + ws[3] + ws[5] + ws[7];
  float mean = S4 * (1.0f / 1024.0f);
  float var = Q4 * (1.0f / 1024.0f) - mean * mean;
  float rstd = rsqrtf(var + 1e-5f);
  float4 sv = *(const float4*)(sc + c);
  float4 bb = *(const float4*)(bi + c);
  u16x4 o;
  o.x = f2bf((a.x - mean) * rstd * sv.x + bb.x);
  o.y = f2bf((a.y - mean) * rstd * sv.y + bb.y);
  o.z = f2bf((a.z - mean) * rstd * sv.z + bb.z);
  o.w = f2bf((a.w - mean) * rstd * sv.w + bb.w);
  *(u16x4*)(h + (size_t)(m * 8 + 7) * 1024 + c) = o;
#pragma unroll
  for (int rr = 0; rr < 2; ++rr) {
    int r = wid * 2 + rr;
    if (r < 7) ln_row(z, m * 8 + r, sc, bi, h);
  }
}

// ---------- LayerNorm kernel (wave per row) ----------
__global__ __launch_bounds__(256) void ln_kernel(const unsigned short* __restrict__ z,
                                                 const float* __restrict__ sc,
                                                 const float* __restrict__ bi,
                                                 unsigned short* __restrict__ h) {
  int row = blockIdx.x * 4 + (threadIdx.x >> 6);
  ln_row(z, row, sc, bi, h);
}

// ---------- standalone GEMM wrapper, XCD-clustered by my ----------
template <int TN, int ACT, int OMODE, bool RES, int BK>
__global__ __launch_bounds__(256) void gemm_k(
    const unsigned short* __restrict__ A, int lda,
    const unsigned short* __restrict__ BT, int ldb, int Kloop,
    const float* __restrict__ bias, const unsigned short* __restrict__ res,
    float* __restrict__ outF, unsigned short* __restrict__ outB,
    int ldC, int Nstore) {
  constexpr int BUFS = (128 + TN) * BK * 2;
  __shared__ __align__(16) char smem[3 * BUFS];
  int p = blockIdx.x;
  int xslot = p & 7, rem = p >> 3;
  int nx = rem & 15;
  int my = xslot + 8 * (rem >> 4);     // 0..15
  gemm_tile<TN, ACT, OMODE, RES, BK>(smem, A, lda, BT, ldb, Kloop, bias, res, outF, outB,
                                     ldC, Nstore, my * 128, nx * TN, 0);
}

// ---------- k_cls: cls GEMM split-K x8 (XCD-clustered) + transform head ----------
__global__ __launch_bounds__(256) void k_cls(
    const unsigned short* __restrict__ z, const unsigned short* __restrict__ BT_cls,
    float* __restrict__ part, const float* __restrict__ w_tr,
    const float* __restrict__ b_tr, float* __restrict__ outF) {
  __shared__ __align__(16) char smem[73728];
  int bid = blockIdx.x;
  int tid = threadIdx.x;
  if (bid < 256) {
    int xslot = bid & 7, rem = bid >> 3;
    int nx = rem & 15, chi = rem >> 4;
    int c = xslot + 8 * chi;
    int sk = c >> 1, my = c & 1;
    gemm_tile<64, 0, 0, false, 64>(smem, z, 8192, BT_cls, 8192, 1024,
                                   nullptr, nullptr, part + (size_t)sk * 262144, nullptr,
                                   1024, 1024, my * 128, nx * 64, sk * 1024);
  } else {
    int m = bid - 256;
    const unsigned short* row = z + (size_t)m * 8192;
    float a0 = 0.f, a1 = 0.f, a2 = 0.f, a3 = 0.f;
    for (int k = tid; k < 8192; k += 256) {
      float xv = bf2f(row[k]);
      const float* wr = w_tr + (size_t)k * 4;
      a0 += xv * wr[0]; a1 += xv * wr[1]; a2 += xv * wr[2]; a3 += xv * wr[3];
    }
    float (*red)[4] = (float (*)[4])smem;
    red[tid][0] = a0; red[tid][1] = a1; red[tid][2] = a2; red[tid][3] = a3;
    __syncthreads();
    for (int s = 128; s > 0; s >>= 1) {
      if (tid < s) {
#pragma unroll
        for (int o = 0; o < 4; o++) red[tid][o] += red[tid + s][o];
      }
      __syncthreads();
    }
    if (tid < 4) {
      float v = red[0][tid] + b_tr[tid];
      outF[256000 + m * 4 + tid] = 1.0f / (1.0f + expf(-v));
    }
  }
}

// ---------- cls reduce -> outF[:, :1000] ----------
__global__ __launch_bounds__(256) void clsred(const float* __restrict__ part,
                                              const float* __restrict__ b_cls,
                                              float* __restrict__ outF) {
  int m = blockIdx.x, c = threadIdx.x * 4;
  float4 a = {0.f, 0.f, 0.f, 0.f};
  for (int p = 0; p < 8; ++p) {
    float4 v = *(const float4*)(part + (size_t)p * 262144 + m * 1024 + c);
    a.x += v.x; a.y += v.y; a.z += v.z; a.w += v.w;
  }
  if (c >= 1000) return;
  float* drow = outF + (size_t)m * 1000;
  float vals[4] = {a.x, a.y, a.z, a.w};
  if (c + 3 < 1000) {
    *(float4*)(drow + c) = make_float4(vals[0] + b_cls[c], vals[1] + b_cls[c + 1],
                                       vals[2] + b_cls[c + 2], vals[3] + b_cls[c + 3]);
  } else {
    for (int j = 0; j < 4 && c + j < 1000; ++j) drow[c + j] = vals[j] + b_cls[c + j];
  }
}

// ---------- launch ----------
extern "C" void kernel_launch(void* const* d_in, const int* in_sizes, int n_in,
                              void* d_out, int out_size, void* d_ws, size_t ws_size,
                              hipStream_t stream) {
  const float* x      = (const float*)d_in[0];
  const float* tr     = (const float*)d_in[1];
  const float* hist   = (const float*)d_in[2];
  const float* w_img  = (const float*)d_in[3];
  const float* b_img  = (const float*)d_in[4];
  const float* ln1_s  = (const float*)d_in[5];
  const float* ln1_b  = (const float*)d_in[6];
  const float* w_qkv  = (const float*)d_in[7];
  const float* w_o    = (const float*)d_in[8];
  const float* b_o    = (const float*)d_in[9];
  const float* ln2_s  = (const float*)d_in[10];
  const float* ln2_b  = (const float*)d_in[11];
  const float* w_ff1  = (const float*)d_in[12];
  const float* b_ff1  = (const float*)d_in[13];
  const float* w_ff2  = (const float*)d_in[14];
  const float* b_ff2  = (const float*)d_in[15];
  const float* w_cls  = (const float*)d_in[16];
  const float* b_cls  = (const float*)d_in[17];
  const float* w_tr   = (const float*)d_in[18];
  const float* b_tr   = (const float*)d_in[19];
  float* outF = (float*)d_out;

  char* w = (char*)d_ws;
  auto alloc = [&](size_t bytes) { char* p = w; w += (bytes + 255) & ~(size_t)255; return p; };
  unsigned short* BT_img = (unsigned short*)alloc((size_t)1024 * 4096 * 2);
  unsigned short* BT_qkv = (unsigned short*)alloc((size_t)4 * 1536 * 1024 * 2);
  unsigned short* BT_o   = (unsigned short*)alloc((size_t)4 * 1024 * 512 * 2);
  unsigned short* BT_ff1 = (unsigned short*)alloc((size_t)4 * 1024 * 1024 * 2);
  unsigned short* BT_ff2 = (unsigned short*)alloc((size_t)4 * 1024 * 1024 * 2);
  unsigned short* BT_cls = (unsigned short*)alloc((size_t)1024 * 8192 * 2);
  unsigned short* feats  = (unsigned short*)alloc((size_t)256 * 4096 * 2);
  unsigned short* z      = (unsigned short*)alloc((size_t)2048 * 1024 * 2);   // bf16 residual stream
  unsigned short* h      = (unsigned short*)alloc((size_t)2048 * 1024 * 2);
  unsigned short* obuf   = (unsigned short*)alloc((size_t)2048 * 512 * 2);
  unsigned short* g      = (unsigned short*)alloc((size_t)2048 * 1024 * 2);
  float*          part   = (float*)alloc((size_t)8 * 256 * 1024 * 4);
  if ((size_t)(w - (char*)d_ws) > ws_size) return;

  front1<<<1280, 256, 0, stream>>>(x, tr, w_img, w_qkv, w_o, w_ff1, w_ff2, w_cls,
                                   BT_img, BT_qkv, BT_o, BT_ff1, BT_ff2, BT_cls, feats);
  k_img<<<8192, 256, 0, stream>>>(feats, BT_img, part, hist, z,
                                  w_img, w_qkv, w_o, w_ff1, w_ff2, w_cls,
                                  BT_img, BT_qkv, BT_o, BT_ff1, BT_ff2, BT_cls);
  imgred_ln<<<256, 256, 0, stream>>>(part, b_img, z, ln1_s, ln1_b, h);

  for (int i = 0; i < 4; ++i) {
    const unsigned short* Wq = BT_qkv + (size_t)i * 1536 * 1024;
    const unsigned short* Wo = BT_o   + (size_t)i * 1024 * 512;
    const unsigned short* W1 = BT_ff1 + (size_t)i * 1024 * 1024;
    const unsigned short* W2 = BT_ff2 + (size_t)i * 1024 * 1024;
    if (i > 0)
      ln_kernel<<<512, 256, 0, stream>>>(z, ln1_s + i * 1024, ln1_b + i * 1024, h);
    qkvattn<<<256, 256, 0, stream>>>(h, Wq, obuf);
    gemm_k<64, 0, 1, true, 64><<<256, 256, 0, stream>>>(
        obuf, 512, Wo, 512, 512, b_o + i * 1024, z, nullptr, z, 1024, 1024);
    ln_kernel<<<512, 256, 0, stream>>>(z, ln2_s + i * 1024, ln2_b + i * 1024, h);
    gemm_k<64, 1, 1, false, 64><<<256, 256, 0, stream>>>(
        h, 1024, W1, 1024, 1024, b_ff1 + i * 1024, nullptr, nullptr, g, 1024, 1024);
    gemm_k<64, 0, 1, true, 64><<<256, 256, 0, stream>>>(
        g, 1024, W2, 1024, 1024, b_ff2 + i * 1024, z, nullptr, z, 1024, 1024);
  }

  k_cls<<<512, 256, 0, stream>>>(z, BT_cls, part, w_tr, b_tr, outF);
  clsred<<<256, 256, 0, stream>>>(part, b_cls, outF);
}